// Round 12
// baseline (97.945 us; speedup 1.0000x reference)
//
#include <hip/hip_runtime.h>

// out[b, m] = sum_n exp(-0.5 * ||inputs[b,n] - stars[m]||^2)
// B=32, N=4096, M=1024, D=3, fp32 in/out.
//
// CALIBRATION ROUND (R11 post-mortem): 11 rounds all fit
//   dur ~= issue_cycles(2.4GHz) + ~19-20us  [offset model]
// but are equally consistent with
//   dur ~= issue_cycles(~1.15GHz), v_exp ~5-7cy, no offset  [clock model].
// This kernel is R11 with the accumulation pass repeated REPEAT=4 times and
// a final exact *0.25f: compute term x4, fixed overhead x1.
//   offset model  -> ~56-62 us
//   clock model   -> >=110 us
// (fp repeat-sum cannot be folded by the compiler without fast-math; loads
// are L1-hot so the repeat adds pure issue cycles.)

#define NB 32
#define NM 1024
#define NN 4096
#define TPB 256
#define MCHUNK 32               // m's per block
#define MPT 8                   // stars per thread
#define NPT 64                  // points per thread (interleaved stride 64)
#define REPEAT 4                // calibration multiplier on compute

__device__ __forceinline__ float exp2_hw(float x) {
    float r;
    asm("v_exp_f32 %0, %1" : "=v"(r) : "v"(x));
    return r;
}

__global__ __launch_bounds__(TPB, 4) void gau_single(const float* __restrict__ inputs,
                                                     const float* __restrict__ stars,
                                                     float* __restrict__ out) {
    constexpr float C2  = 0.72134752044448169f;  // 0.5*log2(e)
    constexpr float L2E = 1.44269504088896340f;  // log2(e)

    const int b  = blockIdx.x >> 5;        // batch
    const int mc = blockIdx.x & 31;        // m-chunk of 32
    const int t  = threadIdx.x;
    const int wv = t >> 6;                 // wave 0..3
    const int mg = t & 3;                  // m-group within chunk
    const int pg = t >> 2;                 // point-group 0..63

    __shared__ float red[4][MCHUNK];       // cross-wave combine (512 B)

    // Per-thread star constants: m = mc*32 + mg*8 + k
    float Sx[MPT], Sy[MPT], Sz[MPT], K[MPT], acc[MPT];
#pragma unroll
    for (int k = 0; k < MPT; ++k) {
        int m = mc * MCHUNK + mg * MPT + k;
        float sx = stars[3 * m + 0];
        float sy = stars[3 * m + 1];
        float sz = stars[3 * m + 2];
        Sx[k] = L2E * sx;
        Sy[k] = L2E * sy;
        Sz[k] = L2E * sz;
        K[k]  = -C2 * (sx * sx + sy * sy + sz * sz);
        acc[k] = 0.0f;
    }

    const float* base = inputs + (size_t)b * NN * 3;

#pragma unroll 1
    for (int rep = 0; rep < REPEAT; ++rep) {
#pragma unroll 4
        for (int i = 0; i < NPT; ++i) {
            const float* p = base + (size_t)(i * 64 + pg) * 3;
            float x = p[0], y = p[1], z = p[2];
            float s2 = x * x;
            s2 = fmaf(y, y, s2);
            s2 = fmaf(z, z, s2);
            float E = exp2_hw(-C2 * s2);
#pragma unroll
            for (int k = 0; k < MPT; ++k) {
                float u = fmaf(z, Sz[k], K[k]);
                u = fmaf(y, Sy[k], u);
                u = fmaf(x, Sx[k], u);
                acc[k] = fmaf(E, exp2_hw(u), acc[k]);
            }
        }
    }

    // Exact rescale: summed REPEAT identical passes -> *1/REPEAT (power of 2).
#pragma unroll
    for (int k = 0; k < MPT; ++k) acc[k] *= (1.0f / REPEAT);

    // Within-wave reduce over the 16 lanes sharing mg (lanes differ in pg bits)
#pragma unroll
    for (int k = 0; k < MPT; ++k) {
        acc[k] += __shfl_xor(acc[k], 4, 64);
        acc[k] += __shfl_xor(acc[k], 8, 64);
        acc[k] += __shfl_xor(acc[k], 16, 64);
        acc[k] += __shfl_xor(acc[k], 32, 64);
    }

    // Lane mg (0..3) of each wave holds the wave's sum for its 8 m's.
    if ((t & 63) < 4) {
#pragma unroll
        for (int k = 0; k < MPT; ++k) {
            red[wv][mg * MPT + k] = acc[k];
        }
    }
    __syncthreads();

    // First 32 threads: combine 4 waves, write out[b*1024 + mc*32 + j].
    if (t < MCHUNK) {
        float s = red[0][t] + red[1][t] + red[2][t] + red[3][t];
        out[(size_t)b * NM + mc * MCHUNK + t] = s;
    }
}

extern "C" void kernel_launch(void* const* d_in, const int* in_sizes, int n_in,
                              void* d_out, int out_size, void* d_ws, size_t ws_size,
                              hipStream_t stream) {
    const float* inputs = (const float*)d_in[0];  // (32, 4096, 3)
    const float* stars  = (const float*)d_in[1];  // (1024, 3)
    float* out = (float*)d_out;                   // (32, 1024)

    gau_single<<<NB * 32, TPB, 0, stream>>>(inputs, stars, out);
}

// Round 13
// 29.272 us; speedup vs baseline: 3.3461x; 3.3461x over previous
//
#include <hip/hip_runtime.h>

// out[b, m] = sum_n exp(-0.5 * ||inputs[b,n] - stars[m]||^2)
// B=32, N=4096, M=1024, D=3, fp32 in/out.
//
// R12 calibration verdict: dur = issue_cycles(2.4GHz) + ~5.5us, with
// v_exp_f32 ~15.4cy/wave issue-blocking (trans does NOT hide under VALU),
// VALU 2cy, v_cvt ~8cy (kills Schraudolph: R4 explained). MFMA null at K=3.
// R5 (27.3us) sits exactly on the serial-issue floor: per term 3fma(6) +
// exp(16) + acc-fma(2) = 24cy -> 20.5us + 1.6 staging + 5.2 offset.
// FINAL LEVER: is exp 16cy hard occupancy, or 8cy + re-arbitration bubbles?
// This kernel = R5 with the inner loop re-ordered into clustered batches:
//   8 dots (24 fma) -> 8 exps back-to-back -> 8 acc-fma
// identical instruction count; pure scheduling A/B vs R5's interleaved order.
// If clustered exps pipeline: 21-24us. If null (27-29): roofline declared.

#define NB 32
#define NN 4096
#define NM 1024
#define NCHUNK 32               // blocks per batch along N
#define NPB (NN / NCHUNK)       // 128 points per block
#define NPAIR (NPB / 2)         // 64 packed pairs
#define TPB 256                 // threads per block (4 waves)
#define MPT (NM / TPB)          // 4 stars per thread

__device__ __forceinline__ float exp2_hw(float x) {
    float r;
    asm("v_exp_f32 %0, %1" : "=v"(r) : "v"(x));
    return r;
}

__global__ __launch_bounds__(TPB, 4) void gau_part(const float* __restrict__ inputs,
                                                   const float* __restrict__ stars,
                                                   float* __restrict__ part) {
    constexpr float C2  = 0.72134752044448169f;  // 0.5*log2(e)
    constexpr float L2E = 1.44269504088896340f;  // log2(e)

    const int b     = blockIdx.x / NCHUNK;
    const int chunk = blockIdx.x % NCHUNK;
    const int t     = threadIdx.x;

    // Pair-packed point tiles: XY[i] = (x0,x1,y0,y1), ZE[i] = (z0,z1,E0,E1)
    __shared__ float4 XY[NPAIR];
    __shared__ float4 ZE[NPAIR];

    if (t < NPAIR) {
        const float* p = inputs + ((size_t)b * NN + (size_t)chunk * NPB + 2 * (size_t)t) * 3;
        float x0 = p[0], y0 = p[1], z0 = p[2];
        float x1 = p[3], y1 = p[4], z1 = p[5];
        float q0 = -C2 * x0 * x0 - C2 * y0 * y0 - C2 * z0 * z0;
        float q1 = -C2 * x1 * x1 - C2 * y1 * y1 - C2 * z1 * z1;
        XY[t] = make_float4(x0, x1, y0, y1);
        ZE[t] = make_float4(z0, z1, exp2_hw(q0), exp2_hw(q1));
    }

    // Per-thread star constants
    float Sx[MPT], Sy[MPT], Sz[MPT], K[MPT], acc[MPT];
#pragma unroll
    for (int k = 0; k < MPT; ++k) {
        int m = t + k * TPB;
        float sx = stars[3 * m + 0];
        float sy = stars[3 * m + 1];
        float sz = stars[3 * m + 2];
        Sx[k] = L2E * sx;
        Sy[k] = L2E * sy;
        Sz[k] = L2E * sz;
        K[k]  = -C2 * (sx * sx + sy * sy + sz * sz);
        acc[k] = 0.0f;
    }

    __syncthreads();

#pragma unroll 2
    for (int i = 0; i < NPAIR; ++i) {
        float4 xy = XY[i];  // uniform address -> LDS broadcast
        float4 ze = ZE[i];
        float u[2 * MPT], e[2 * MPT];
        // ---- batch 1: all 8 dot chains (24 fma, independent) ----
#pragma unroll
        for (int k = 0; k < MPT; ++k) {
            u[2 * k]     = fmaf(xy.x, Sx[k], fmaf(xy.z, Sy[k], fmaf(ze.x, Sz[k], K[k])));
            u[2 * k + 1] = fmaf(xy.y, Sx[k], fmaf(xy.w, Sy[k], fmaf(ze.y, Sz[k], K[k])));
        }
        // ---- batch 2: 8 exps back-to-back (trans pipeline test) ----
#pragma unroll
        for (int j = 0; j < 2 * MPT; ++j) {
            e[j] = exp2_hw(u[j]);
        }
        // ---- batch 3: 8 accumulate fmas ----
#pragma unroll
        for (int k = 0; k < MPT; ++k) {
            acc[k] = fmaf(ze.z, e[2 * k], acc[k]);
            acc[k] = fmaf(ze.w, e[2 * k + 1], acc[k]);
        }
    }

    // Coalesced partial store: part[(b*NCHUNK + chunk)*NM + m]
    float* pb = part + ((size_t)b * NCHUNK + chunk) * NM;
#pragma unroll
    for (int k = 0; k < MPT; ++k) {
        pb[t + k * TPB] = acc[k];
    }
}

__global__ __launch_bounds__(256) void gau_reduce(const float* __restrict__ part,
                                                  float* __restrict__ out) {
    const int o = blockIdx.x * 256 + threadIdx.x;  // o = b*NM + m, 32K total
    const int b = o >> 10;
    const int m = o & (NM - 1);
    const float* pb = part + (size_t)b * NCHUNK * NM + m;
    float s = 0.0f;
#pragma unroll
    for (int c = 0; c < NCHUNK; ++c) {
        s += pb[(size_t)c * NM];  // adjacent lanes -> adjacent m: coalesced
    }
    out[o] = s;
}

extern "C" void kernel_launch(void* const* d_in, const int* in_sizes, int n_in,
                              void* d_out, int out_size, void* d_ws, size_t ws_size,
                              hipStream_t stream) {
    const float* inputs = (const float*)d_in[0];  // (32, 4096, 3)
    const float* stars  = (const float*)d_in[1];  // (1024, 3)
    float* out  = (float*)d_out;                  // (32, 1024)
    float* part = (float*)d_ws;                   // (32*32, 1024) = 4 MB

    gau_part<<<NB * NCHUNK, TPB, 0, stream>>>(inputs, stars, part);
    gau_reduce<<<(NB * NM) / 256, 256, 0, stream>>>(part, out);
}